// Round 14
// baseline (186.394 us; speedup 1.0000x reference)
//
#include <hip/hip_runtime.h>
#include <hip/hip_bf16.h>

#define NN 50000
#define EE 640000
#define HD 128
#define NCLS 40
#define BN_EPS 1e-5f
#define GTILES 1563  // ceil(NN/32)
#define GGRID 782    // gemm grid: each block does tiles {bid, bid+GGRID}
#define NB 98        // dst buckets of 512 nodes
#define ECHUNK 5000  // EE / 128

typedef short bf16x8 __attribute__((ext_vector_type(8)));
typedef float f32x4 __attribute__((ext_vector_type(4)));

__device__ __forceinline__ short f2bf(float f) {
    __hip_bfloat16 h = __float2bfloat16(f);
    return *reinterpret_cast<short*>(&h);
}
__device__ __forceinline__ float bflo(unsigned int v) { return __uint_as_float(v << 16); }
__device__ __forceinline__ float bfhi(unsigned int v) { return __uint_as_float(v & 0xffff0000u); }
__device__ __forceinline__ unsigned int packbf(float a, float b) {
    return (unsigned)(unsigned short)f2bf(a) | ((unsigned)(unsigned short)f2bf(b) << 16);
}

// ---------------- edge_index width detect ----------------
__global__ void detect_kernel(const void* __restrict__ ei, int* __restrict__ flag) {
    int t = threadIdx.x;  // 256
    const long long* p = (const long long*)ei;
    long long v = p[(size_t)t * (EE / 256)];
    if (v < 0 || v >= NN) atomicOr(flag, 1);  // flag=1 -> int32 data
}

// ---------------- per-(block,bucket) histogram (LDS only) ----------------
__global__ __launch_bounds__(512) void hist_kernel(const void* __restrict__ ei,
                                                   const int* __restrict__ flag,
                                                   int* __restrict__ cnt) {
    __shared__ int lh[NB];
    int t = threadIdx.x, b = blockIdx.x;
    if (t < NB) lh[t] = 0;
    __syncthreads();
    bool narrow = (*flag != 0);
    int e0 = b * ECHUNK;
    for (int e = e0 + t; e < e0 + ECHUNK; e += 512) {
        int d = narrow ? ((const int*)ei)[EE + e] : (int)((const long long*)ei)[EE + e];
        atomicAdd(&lh[d >> 9], 1);
    }
    __syncthreads();
    if (t < NB) cnt[b * NB + t] = lh[t];
}

// ---------------- bucket bases + per-(block,bucket) scatter offsets ----------------
__global__ void bucket_off2(const int* __restrict__ cnt, int* __restrict__ boffs,
                            int* __restrict__ ebase) {
    __shared__ int s[128];
    int k = threadIdx.x;  // 0..127, NB active
    int tot = 0;
    if (k < NB)
        for (int b = 0; b < 128; ++b) tot += cnt[b * NB + k];
    s[k] = tot;
    __syncthreads();
    for (int o = 1; o < 128; o <<= 1) {
        int u = (k >= o) ? s[k - o] : 0;
        __syncthreads();
        s[k] += u;
        __syncthreads();
    }
    if (k < NB) {
        int base = s[k] - tot;  // exclusive
        ebase[k] = base;
        if (k == NB - 1) ebase[NB] = base + tot;  // = EE
        int run = base;
        for (int b = 0; b < 128; ++b) {
            boffs[b * NB + k] = run;
            run += cnt[b * NB + k];
        }
    }
}

// ---------------- scatter edges (packed: dstLocal<<17 | src) ----------
__global__ __launch_bounds__(512) void bucket_scatter(const void* __restrict__ ei,
                                                      const int* __restrict__ flag,
                                                      const int* __restrict__ boffs,
                                                      unsigned int* __restrict__ bkt) {
    __shared__ int lc[NB];
    int t = threadIdx.x, b = blockIdx.x;
    if (t < NB) lc[t] = boffs[b * NB + t];
    __syncthreads();
    bool narrow = (*flag != 0);
    int e0 = b * ECHUNK;
    for (int e = e0 + t; e < e0 + ECHUNK; e += 512) {
        int s, d;
        if (narrow) {
            s = ((const int*)ei)[e];
            d = ((const int*)ei)[EE + e];
        } else {
            s = (int)((const long long*)ei)[e];
            d = (int)((const long long*)ei)[EE + e];
        }
        int pos = atomicAdd(&lc[d >> 9], 1);
        bkt[pos] = ((unsigned)(d & 511) << 17) | (unsigned)s;
    }
}

// ---------------- per-bucket CSR build: LDS degree+scan+adj image, coalesced out --------
__global__ __launch_bounds__(512) void bucket_build(const unsigned int* __restrict__ bkt,
                                                    const int* __restrict__ ebase,
                                                    int* __restrict__ rowptr,
                                                    float* __restrict__ invdeg,
                                                    int* __restrict__ adj) {
    __shared__ int ldeg[512];
    __shared__ int lcur[512];
    __shared__ int ladj[8192];
    int t = threadIdx.x, k = blockIdx.x;
    int nodeBase = k << 9;
    int nn = NN - nodeBase;
    if (nn > 512) nn = 512;
    int e0 = ebase[k], e1 = ebase[k + 1];
    int ne = e1 - e0;
    ldeg[t] = 0;
    __syncthreads();
    for (int i = e0 + t; i < e1; i += 512)
        atomicAdd(&ldeg[bkt[i] >> 17], 1);
    __syncthreads();
    int d = ldeg[t];
    lcur[t] = d;
    __syncthreads();
    for (int o = 1; o < 512; o <<= 1) {  // inclusive scan
        int u = (t >= o) ? lcur[t - o] : 0;
        __syncthreads();
        lcur[t] += u;
        __syncthreads();
    }
    int excl = lcur[t] - d;
    if (t < nn) {
        rowptr[nodeBase + t] = e0 + excl;
        invdeg[nodeBase + t] = 1.0f / (float)(d > 1 ? d : 1);
    }
    if (k == 0 && t == 0) rowptr[NN] = EE;
    __syncthreads();
    lcur[t] = excl;  // reuse as cursor
    __syncthreads();
    if (ne <= 8192) {
        for (int i = e0 + t; i < e1; i += 512) {
            unsigned int p = bkt[i];
            int pos = atomicAdd(&lcur[p >> 17], 1);
            ladj[pos] = (int)(p & 0x1FFFFu);
        }
        __syncthreads();
        for (int i = t; i < ne; i += 512) adj[e0 + i] = ladj[i];
    } else {  // overflow fallback (never for this graph; correctness net)
        for (int i = e0 + t; i < e1; i += 512) {
            unsigned int p = bkt[i];
            int pos = atomicAdd(&lcur[p >> 17], 1);
            adj[e0 + pos] = (int)(p & 0x1FFFFu);
        }
    }
}

// ---------------- merged weight prep: y<4 combine; y==4 fc0->bf16; y==5 out_w->bf16x48 --
__global__ void prep_w(const float* __restrict__ Ww, const float* __restrict__ linl,
                       const float* __restrict__ linr, const float* __restrict__ fc0w,
                       const float* __restrict__ outw, ushort* __restrict__ Wcb,
                       ushort* __restrict__ wfc0, ushort* __restrict__ wo48) {
    __shared__ float wrow[HD];
    int k = threadIdx.x;
    int m = blockIdx.x;
    int which = blockIdx.y;
    if (which < 4) {  // Wc[which] = bf16(W_w @ lin_{l/r}[layer])
        const float* lin = ((which & 1) ? linr : linl) + (which >> 1) * HD * HD;
        wrow[k] = Ww[m * HD + k];
        __syncthreads();
        float acc = 0.f;
        for (int j = 0; j < HD; ++j) acc += wrow[j] * lin[j * HD + k];
        Wcb[which * HD * HD + m * HD + k] = (unsigned short)f2bf(acc);
    } else if (which == 4) {
        wfc0[m * HD + k] = (unsigned short)f2bf(fc0w[m * HD + k]);
    } else {
        if (m < 48) wo48[m * HD + k] = (m < NCLS) ? (unsigned short)f2bf(outw[m * HD + k]) : (unsigned short)0;
    }
}

// ---------------- fc0 GEMM: fp32 A staged->bf16, LDS, pipelined, stat partials ----------
__global__ __launch_bounds__(256) void gemm_fc0(const float* __restrict__ X,
                                                const ushort* __restrict__ W1,
                                                ushort* __restrict__ Y,
                                                float* __restrict__ parts) {
    __shared__ __align__(16) char lds[32768];
    const int t = threadIdx.x;
    const int l = t & 63, w = t >> 6;
    const int lr = l & 15, lg = l >> 4;

    bf16x8 bw1[2][4];
    {
        const uint4* srcw = (const uint4*)W1;
        for (int i = t; i < 2048; i += 256) ((uint4*)lds)[i] = srcw[i];
        __syncthreads();
#pragma unroll
        for (int cc = 0; cc < 2; ++cc)
#pragma unroll
            for (int kk = 0; kk < 4; ++kk)
                bw1[cc][kk] = *(const bf16x8*)&lds[((w * 2 + cc) * 16 + lr) * 256 + kk * 64 + lg * 16];
        __syncthreads();
    }

    const int t0 = blockIdx.x;
    const int t1 = blockIdx.x + GGRID;
    const bool has2 = (t1 < GTILES);

    f32x4 ss[2] = {}, sq[2] = {};
    uint4 fx[4];
    auto stage_load = [&](int tile) {
#pragma unroll
        for (int s = 0; s < 2; ++s) {
            int o = s * 4096 + t * 16;
            int po = o ^ (((o >> 8) & 7) << 4);
            int grow = tile * 32 + (po >> 8);
            if (grow > NN - 1) grow = NN - 1;
            const char* src = (const char*)X + (size_t)grow * 512 + (size_t)(po & 255) * 2;
            fx[s * 2] = *(const uint4*)src;
            fx[s * 2 + 1] = *(const uint4*)(src + 16);
        }
    };
    auto stage_write = [&](int buf) {
        char* base = lds + buf * 8192;
#pragma unroll
        for (int s = 0; s < 2; ++s) {
            uint4 a = fx[s * 2], b2 = fx[s * 2 + 1];
            uint4 v;
            v.x = packbf(__uint_as_float(a.x), __uint_as_float(a.y));
            v.y = packbf(__uint_as_float(a.z), __uint_as_float(a.w));
            v.z = packbf(__uint_as_float(b2.x), __uint_as_float(b2.y));
            v.w = packbf(__uint_as_float(b2.z), __uint_as_float(b2.w));
            *(uint4*)(base + s * 4096 + t * 16) = v;
        }
    };
    auto compute = [&](int tile, int buf) {
        const char* base = lds + buf * 8192;
        f32x4 acc[2][2] = {};
#pragma unroll
        for (int rf = 0; rf < 2; ++rf) {
            int rowb = (rf * 16 + lr) * 256;
            int sw = (lr & 7) << 4;
            bf16x8 a1[4];
#pragma unroll
            for (int kk = 0; kk < 4; ++kk)
                a1[kk] = *(const bf16x8*)(base + rowb + ((kk * 64 + lg * 16) ^ sw));
#pragma unroll
            for (int kk = 0; kk < 4; ++kk)
#pragma unroll
                for (int cc = 0; cc < 2; ++cc)
                    acc[rf][cc] = __builtin_amdgcn_mfma_f32_16x16x32_bf16(bw1[cc][kk], a1[kk], acc[rf][cc], 0, 0, 0);
        }
#pragma unroll
        for (int rf = 0; rf < 2; ++rf) {
            int row = tile * 32 + rf * 16 + lr;
            if (row < NN) {
#pragma unroll
                for (int cc = 0; cc < 2; ++cc) {
                    f32x4 v = acc[rf][cc];
                    uint2 o;
                    o.x = packbf(v[0], v[1]);
                    o.y = packbf(v[2], v[3]);
                    *(uint2*)&Y[(size_t)row * HD + (w * 2 + cc) * 16 + lg * 4] = o;
                    ss[cc] += v;
                    sq[cc] += v * v;
                }
            }
        }
    };

    stage_load(t0);
    stage_write(0);
    if (has2) stage_load(t1);
    __syncthreads();
    compute(t0, 0);
    if (has2) {
        stage_write(1);
        __syncthreads();
        compute(t1, 1);
    }

#pragma unroll
    for (int cc = 0; cc < 2; ++cc)
#pragma unroll
        for (int j = 0; j < 4; ++j) {
            float a = ss[cc][j], b = sq[cc][j];
#pragma unroll
            for (int m = 1; m < 16; m <<= 1) {
                a += __shfl_xor(a, m);
                b += __shfl_xor(b, m);
            }
            if (lr == 0) {
                int col = (w * 2 + cc) * 16 + lg * 4 + j;
                parts[(size_t)col * GTILES + blockIdx.x] = a;
                parts[(size_t)(HD + col) * GTILES + blockIdx.x] = b;
            }
        }
}

// ---------------- dual GEMM: Y = bf16(A1@W1^T + relu(bn(A2))@W2^T) + stat partials -------
__global__ __launch_bounds__(256) void gemm_dual(const ushort* __restrict__ A1g,
                                                 const ushort* __restrict__ A2g,
                                                 const float* __restrict__ bnp,
                                                 const ushort* __restrict__ W1,
                                                 const ushort* __restrict__ W2,
                                                 ushort* __restrict__ Y,
                                                 float* __restrict__ parts) {
    __shared__ __align__(16) char lds[32768];
    const int t = threadIdx.x;
    const int l = t & 63, w = t >> 6;
    const int lr = l & 15, lg = l >> 4;

    bf16x8 bw1[2][4], bw2[2][4];
    {
        const uint4* srcw = (const uint4*)W1;
        for (int i = t; i < 2048; i += 256) ((uint4*)lds)[i] = srcw[i];
        __syncthreads();
#pragma unroll
        for (int cc = 0; cc < 2; ++cc)
#pragma unroll
            for (int kk = 0; kk < 4; ++kk)
                bw1[cc][kk] = *(const bf16x8*)&lds[((w * 2 + cc) * 16 + lr) * 256 + kk * 64 + lg * 16];
        __syncthreads();
        const uint4* srcw2 = (const uint4*)W2;
        for (int i = t; i < 2048; i += 256) ((uint4*)lds)[i] = srcw2[i];
        __syncthreads();
#pragma unroll
        for (int cc = 0; cc < 2; ++cc)
#pragma unroll
            for (int kk = 0; kk < 4; ++kk)
                bw2[cc][kk] = *(const bf16x8*)&lds[((w * 2 + cc) * 16 + lr) * 256 + kk * 64 + lg * 16];
        __syncthreads();
    }

    const int t0 = blockIdx.x;
    const int t1 = blockIdx.x + GGRID;
    const bool has2 = (t1 < GTILES);

    f32x4 ss[2] = {}, sq[2] = {};

    uint4 st1[2], st2[2];
    auto stage_load = [&](int tile) {
#pragma unroll
        for (int s = 0; s < 2; ++s) {
            int o = s * 4096 + t * 16;
            int po = o ^ (((o >> 8) & 7) << 4);
            int grow = tile * 32 + (po >> 8);
            if (grow > NN - 1) grow = NN - 1;
            st1[s] = *(const uint4*)((const char*)A1g + (size_t)grow * 256 + (po & 255));
            st2[s] = *(const uint4*)((const char*)A2g + (size_t)grow * 256 + (po & 255));
        }
    };
    auto stage_write = [&](int buf) {
        char* base = lds + buf * 16384;
#pragma unroll
        for (int s = 0; s < 2; ++s) {
            int o = s * 4096 + t * 16;
            *(uint4*)(base + o) = st1[s];
            int po = o ^ (((o >> 8) & 7) << 4);
            int col0 = (po & 255) >> 1;  // 8 consecutive cols
            float4 sa = *(const float4*)&bnp[col0];
            float4 sb = *(const float4*)&bnp[col0 + 4];
            float4 ba = *(const float4*)&bnp[HD + col0];
            float4 bb2 = *(const float4*)&bnp[HD + col0 + 4];
            uint4 h;
            h.x = packbf(fmaxf(bflo(st2[s].x) * sa.x + ba.x, 0.f),
                         fmaxf(bfhi(st2[s].x) * sa.y + ba.y, 0.f));
            h.y = packbf(fmaxf(bflo(st2[s].y) * sa.z + ba.z, 0.f),
                         fmaxf(bfhi(st2[s].y) * sa.w + ba.w, 0.f));
            h.z = packbf(fmaxf(bflo(st2[s].z) * sb.x + bb2.x, 0.f),
                         fmaxf(bfhi(st2[s].z) * sb.y + bb2.y, 0.f));
            h.w = packbf(fmaxf(bflo(st2[s].w) * sb.z + bb2.z, 0.f),
                         fmaxf(bfhi(st2[s].w) * sb.w + bb2.w, 0.f));
            *(uint4*)(base + 8192 + o) = h;
        }
    };
    auto compute = [&](int tile, int buf) {
        const char* base = lds + buf * 16384;
        f32x4 acc[2][2] = {};
#pragma unroll
        for (int rf = 0; rf < 2; ++rf) {
            int rowb = (rf * 16 + lr) * 256;
            int sw = (lr & 7) << 4;
            bf16x8 a1[4], a2[4];
#pragma unroll
            for (int kk = 0; kk < 4; ++kk) {
                int q = rowb + ((kk * 64 + lg * 16) ^ sw);
                a1[kk] = *(const bf16x8*)(base + q);
                a2[kk] = *(const bf16x8*)(base + 8192 + q);
            }
#pragma unroll
            for (int kk = 0; kk < 4; ++kk)
#pragma unroll
                for (int cc = 0; cc < 2; ++cc) {
                    acc[rf][cc] = __builtin_amdgcn_mfma_f32_16x16x32_bf16(bw1[cc][kk], a1[kk], acc[rf][cc], 0, 0, 0);
                    acc[rf][cc] = __builtin_amdgcn_mfma_f32_16x16x32_bf16(bw2[cc][kk], a2[kk], acc[rf][cc], 0, 0, 0);
                }
        }
#pragma unroll
        for (int rf = 0; rf < 2; ++rf) {
            int row = tile * 32 + rf * 16 + lr;
            if (row < NN) {
#pragma unroll
                for (int cc = 0; cc < 2; ++cc) {
                    f32x4 v = acc[rf][cc];
                    uint2 o;
                    o.x = packbf(v[0], v[1]);
                    o.y = packbf(v[2], v[3]);
                    *(uint2*)&Y[(size_t)row * HD + (w * 2 + cc) * 16 + lg * 4] = o;
                    ss[cc] += v;
                    sq[cc] += v * v;
                }
            }
        }
    };

    stage_load(t0);
    stage_write(0);
    if (has2) stage_load(t1);  // in flight during compute(t0)
    __syncthreads();
    compute(t0, 0);
    if (has2) {
        stage_write(1);
        __syncthreads();
        compute(t1, 1);
    }

#pragma unroll
    for (int cc = 0; cc < 2; ++cc)
#pragma unroll
        for (int j = 0; j < 4; ++j) {
            float a = ss[cc][j], b = sq[cc][j];
#pragma unroll
            for (int m = 1; m < 16; m <<= 1) {
                a += __shfl_xor(a, m);
                b += __shfl_xor(b, m);
            }
            if (lr == 0) {
                int col = (w * 2 + cc) * 16 + lg * 4 + j;
                parts[(size_t)col * GTILES + blockIdx.x] = a;
                parts[(size_t)(HD + col) * GTILES + blockIdx.x] = b;
            }
        }
}

// ---------------- BN fold: block j reduces n partials for col j -> bnp ----------------
__global__ __launch_bounds__(256) void bn_fold2(const float* __restrict__ parts, int n,
                                                const float* __restrict__ scale,
                                                const float* __restrict__ bias,
                                                float* __restrict__ bnp) {
    __shared__ float r1[256], r2[256];
    int j = blockIdx.x;   // 0..127 column
    int t = threadIdx.x;  // 256
    float a = 0.f, b = 0.f;
    for (int i = t; i < n; i += 256) {
        a += parts[(size_t)j * GTILES + i];
        b += parts[(size_t)(HD + j) * GTILES + i];
    }
    r1[t] = a; r2[t] = b;
    __syncthreads();
    for (int o = 128; o; o >>= 1) {
        if (t < o) { r1[t] += r1[t + o]; r2[t] += r2[t + o]; }
        __syncthreads();
    }
    if (t == 0) {
        float mu = r1[0] * (1.0f / NN);
        float var = r2[0] * (1.0f / NN) - mu * mu;
        float sc = scale[j] * rsqrtf(var + BN_EPS);
        bnp[j] = sc;
        bnp[HD + j] = bias[j] - mu * sc;
    }
}

// ---------------- aggregation v4: 16 neighbors in flight, BN+ReLU fused ----------------
__global__ __launch_bounds__(256) void agg_kernel(const ushort* __restrict__ Hp,
                                                  const float* __restrict__ bnp,
                                                  const int* __restrict__ adj,
                                                  const int* __restrict__ rowptr,
                                                  const float* __restrict__ invdeg,
                                                  ushort* __restrict__ A) {
    int node = blockIdx.x * 4 + (threadIdx.x >> 6);
    if (node >= NN) return;
    int l = threadIdx.x & 63;
    int slot = l >> 4, col = l & 15;
    float sc[8], bi[8];
    {
        float4 a = *(const float4*)&bnp[col * 8];
        float4 b = *(const float4*)&bnp[col * 8 + 4];
        float4 c = *(const float4*)&bnp[HD + col * 8];
        float4 d = *(const float4*)&bnp[HD + col * 8 + 4];
        sc[0] = a.x; sc[1] = a.y; sc[2] = a.z; sc[3] = a.w;
        sc[4] = b.x; sc[5] = b.y; sc[6] = b.z; sc[7] = b.w;
        bi[0] = c.x; bi[1] = c.y; bi[2] = c.z; bi[3] = c.w;
        bi[4] = d.x; bi[5] = d.y; bi[6] = d.z; bi[7] = d.w;
    }
    int b = rowptr[node], e = rowptr[node + 1];
    float id = invdeg[node];
    float acc[8] = {};
    for (int i = b; i < e; i += 16) {
        int i0 = i + slot, i1 = i + 4 + slot, i2 = i + 8 + slot, i3 = i + 12 + slot;
        bool v0 = i0 < e, v1 = i1 < e, v2 = i2 < e, v3 = i3 < e;
        int s0 = adj[v0 ? i0 : i];
        int s1 = adj[v1 ? i1 : i];
        int s2 = adj[v2 ? i2 : i];
        int s3 = adj[v3 ? i3 : i];
        uint4 a0 = *(const uint4*)&Hp[(size_t)s0 * HD + col * 8];
        uint4 a1 = *(const uint4*)&Hp[(size_t)s1 * HD + col * 8];
        uint4 a2 = *(const uint4*)&Hp[(size_t)s2 * HD + col * 8];
        uint4 a3 = *(const uint4*)&Hp[(size_t)s3 * HD + col * 8];
        float m0 = v0 ? 1.f : 0.f, m1 = v1 ? 1.f : 0.f;
        float m2 = v2 ? 1.f : 0.f, m3 = v3 ? 1.f : 0.f;
#define TERM(k, lo, word)                                                            \
        acc[k] += fmaxf(lo(a0.word) * sc[k] + bi[k], 0.f) * m0 +                      \
                  fmaxf(lo(a1.word) * sc[k] + bi[k], 0.f) * m1 +                      \
                  fmaxf(lo(a2.word) * sc[k] + bi[k], 0.f) * m2 +                      \
                  fmaxf(lo(a3.word) * sc[k] + bi[k], 0.f) * m3
        TERM(0, bflo, x); TERM(1, bfhi, x);
        TERM(2, bflo, y); TERM(3, bfhi, y);
        TERM(4, bflo, z); TERM(5, bfhi, z);
        TERM(6, bflo, w); TERM(7, bfhi, w);
#undef TERM
    }
#pragma unroll
    for (int c2 = 0; c2 < 8; ++c2) {
        acc[c2] += __shfl_xor(acc[c2], 16);
        acc[c2] += __shfl_xor(acc[c2], 32);
    }
    if (slot == 0) {
        uint4 o;
        o.x = packbf(acc[0] * id, acc[1] * id);
        o.y = packbf(acc[2] * id, acc[3] * id);
        o.z = packbf(acc[4] * id, acc[5] * id);
        o.w = packbf(acc[6] * id, acc[7] * id);
        *(uint4*)&A[(size_t)node * HD + col * 8] = o;
    }
}

// ---------------- output: MFMA with fused BN on staging, fp32 out + bias ----------------
__global__ __launch_bounds__(256) void out_mfma(const ushort* __restrict__ Hp,
                                                const float* __restrict__ bnp,
                                                const ushort* __restrict__ W48,
                                                const float* __restrict__ B,
                                                float* __restrict__ out) {
    __shared__ __align__(16) char lds[16384];
    __shared__ float blds[48];
    const int t = threadIdx.x;
    const int l = t & 63;
    const int lr = l & 15, lg = l >> 4;
    if (t < 48) blds[t] = (t < NCLS) ? B[t] : 0.f;

    bf16x8 bw[3][4];
#pragma unroll
    for (int cc = 0; cc < 3; ++cc)
#pragma unroll
        for (int kk = 0; kk < 4; ++kk)
            bw[cc][kk] = *(const bf16x8*)&W48[(size_t)(cc * 16 + lr) * HD + kk * 32 + lg * 8];

    const int t0 = blockIdx.x, t1 = blockIdx.x + GGRID;
    const bool has2 = (t1 < GTILES);

    uint4 s1a[2];
    auto stage_load = [&](int tile) {
#pragma unroll
        for (int s = 0; s < 2; ++s) {
            int o = s * 4096 + t * 16;
            int po = o ^ (((o >> 8) & 7) << 4);
            int grow = tile * 32 + (po >> 8);
            if (grow > NN - 1) grow = NN - 1;
            s1a[s] = *(const uint4*)((const char*)Hp + (size_t)grow * 256 + (po & 255));
        }
    };
    auto stage_write = [&](int buf) {
        char* base = lds + buf * 8192;
#pragma unroll
        for (int s = 0; s < 2; ++s) {
            int o = s * 4096 + t * 16;
            int po = o ^ (((o >> 8) & 7) << 4);
            int col0 = (po & 255) >> 1;
            float4 sa = *(const float4*)&bnp[col0];
            float4 sb = *(const float4*)&bnp[col0 + 4];
            float4 ba = *(const float4*)&bnp[HD + col0];
            float4 bb2 = *(const float4*)&bnp[HD + col0 + 4];
            uint4 h;
            h.x = packbf(fmaxf(bflo(s1a[s].x) * sa.x + ba.x, 0.f),
                         fmaxf(bfhi(s1a[s].x) * sa.y + ba.y, 0.f));
            h.y = packbf(fmaxf(bflo(s1a[s].y) * sa.z + ba.z, 0.f),
                         fmaxf(bfhi(s1a[s].y) * sa.w + ba.w, 0.f));
            h.z = packbf(fmaxf(bflo(s1a[s].z) * sb.x + bb2.x, 0.f),
                         fmaxf(bfhi(s1a[s].z) * sb.y + bb2.y, 0.f));
            h.w = packbf(fmaxf(bflo(s1a[s].w) * sb.z + bb2.z, 0.f),
                         fmaxf(bfhi(s1a[s].w) * sb.w + bb2.w, 0.f));
            *(uint4*)(base + o) = h;
        }
    };
    auto compute = [&](int tile, int buf) {
        const char* base = lds + buf * 8192;
        f32x4 acc[2][3] = {};
#pragma unroll
        for (int rf = 0; rf < 2; ++rf) {
            int rowb = (rf * 16 + lr) * 256;
            int sw = (lr & 7) << 4;
            bf16x8 a1[4];
#pragma unroll
            for (int kk = 0; kk < 4; ++kk)
                a1[kk] = *(const bf16x8*)(base + rowb + ((kk * 64 + lg * 16) ^ sw));
#pragma unroll
            for (int kk = 0; kk < 4; ++kk)
#pragma unroll
                for (int cc = 0; cc < 3; ++cc)
                    acc[rf][cc] = __builtin_amdgcn_mfma_f32_16x16x32_bf16(bw[cc][kk], a1[kk], acc[rf][cc], 0, 0, 0);
        }
#pragma unroll
        for (int rf = 0; rf < 2; ++rf) {
            int row = tile * 32 + rf * 16 + lr;
            if (row < NN) {
#pragma unroll
                for (int cc = 0; cc < 3; ++cc) {
                    int col = cc * 16 + lg * 4;
                    if (col < NCLS) {
                        float4 bv = *(const float4*)&blds[col];
                        float2 lo = {acc[rf][cc][0] + bv.x, acc[rf][cc][1] + bv.y};
                        float2 hi = {acc[rf][cc][2] + bv.z, acc[rf][cc][3] + bv.w};
                        *(float2*)&out[(size_t)row * NCLS + col] = lo;
                        *(float2*)&out[(size_t)row * NCLS + col + 2] = hi;
                    }
                }
            }
        }
    };

    stage_load(t0);
    stage_write(0);
    if (has2) stage_load(t1);
    __syncthreads();
    compute(t0, 0);
    if (has2) {
        stage_write(1);
        __syncthreads();
        compute(t1, 1);
    }
}

extern "C" void kernel_launch(void* const* d_in, const int* in_sizes, int n_in,
                              void* d_out, int out_size, void* d_ws, size_t ws_size,
                              hipStream_t stream) {
    const float* x = (const float*)d_in[0];
    const void* ei = d_in[1];
    const float* fc0_w = (const float*)d_in[2];
    const float* bn_scale = (const float*)d_in[4];
    const float* bn_bias = (const float*)d_in[5];
    const float* lin_l = (const float*)d_in[6];
    const float* lin_r = (const float*)d_in[7];
    const float* W_w = (const float*)d_in[8];
    const float* out_w = (const float*)d_in[10];
    const float* out_b = (const float*)d_in[11];
    float* out = (float*)d_out;

    // ---- workspace carve-up (256B aligned) ----
    char* p = (char*)d_ws;
    auto alloc = [&](size_t bytes) -> void* {
        void* r = (void*)p;
        p += (bytes + 255) & ~(size_t)255;
        return r;
    };
    int* eflag = (int*)alloc(256);
    size_t ctrl_bytes = (size_t)(p - (char*)d_ws);
    int* rowptr = (int*)alloc((NN + 1) * 4);
    float* invdeg = (float*)alloc(NN * 4);
    int* adj = (int*)alloc(EE * 4);
    int* cnt = (int*)alloc(128 * NB * 4);
    int* boffs = (int*)alloc(128 * NB * 4);
    int* ebase = (int*)alloc((NB + 1) * 4);
    unsigned int* bkt = (unsigned int*)alloc((size_t)EE * 4);
    float* parts = (float*)alloc((size_t)256 * GTILES * 4);  // stat partials [256][1563]
    float* bnp = (float*)alloc(3 * 256 * 4);        // [3][scale128|bias128]
    ushort* Wcb = (ushort*)alloc(4 * HD * HD * 2);  // [layer][l/r][128][128] bf16
    ushort* wfc0 = (ushort*)alloc(HD * HD * 2);     // fc0_w bf16
    ushort* wo48 = (ushort*)alloc(48 * HD * 2);     // out_w bf16 zero-padded to 48 rows
    ushort* hpreA = (ushort*)alloc((size_t)NN * HD * 2);  // pre-BN activations (bf16)
    ushort* hpreB = (ushort*)alloc((size_t)NN * HD * 2);
    ushort* aggb = (ushort*)alloc((size_t)NN * HD * 2);

    hipMemsetAsync(d_ws, 0, ctrl_bytes, stream);

    // graph build: detect -> hist -> offsets -> scatter -> per-bucket build
    detect_kernel<<<1, 256, 0, stream>>>(ei, eflag);
    hist_kernel<<<128, 512, 0, stream>>>(ei, eflag, cnt);
    bucket_off2<<<1, 128, 0, stream>>>(cnt, boffs, ebase);
    bucket_scatter<<<128, 512, 0, stream>>>(ei, eflag, boffs, bkt);
    bucket_build<<<NB, 512, 0, stream>>>(bkt, ebase, rowptr, invdeg, adj);

    // merged weight prep (combine + fc0 conv + out conv)
    prep_w<<<dim3(HD, 6), HD, 0, stream>>>(W_w, lin_l, lin_r, fc0_w, out_w, Wcb, wfc0, wo48);

    // fc0 (reads fp32 x directly) -> hpreA + stats (fc0_b dropped: cancelled by BN)
    gemm_fc0<<<GGRID, 256, 0, stream>>>(x, wfc0, hpreA, parts);
    bn_fold2<<<128, 256, 0, stream>>>(parts, GGRID, bn_scale, bn_bias, bnp);

    ushort* hcur = hpreA;
    ushort* hnext = hpreB;
    for (int layer = 0; layer < 2; ++layer) {
        float* bp = bnp + layer * 256;
        const ushort* Wl = Wcb + (size_t)(layer * 2 + 0) * HD * HD;
        const ushort* Wr = Wcb + (size_t)(layer * 2 + 1) * HD * HD;
        // agg applies BN+ReLU on the fly from pre-BN hcur (max-occupancy gather dispatch)
        agg_kernel<<<(NN + 3) / 4, 256, 0, stream>>>(hcur, bp, adj, rowptr, invdeg, aggb);
        // fused: hnext = bf16(aggb@Wl^T + relu(bn(hcur))@Wr^T) + stat partials
        gemm_dual<<<GGRID, 256, 0, stream>>>(aggb, hcur, bp, Wl, Wr, hnext, parts);
        bn_fold2<<<128, 256, 0, stream>>>(parts, GGRID, bn_scale + (layer + 1) * HD,
                                          bn_bias + (layer + 1) * HD, bnp + (layer + 1) * 256);
        ushort* tmp = hcur; hcur = hnext; hnext = tmp;
    }

    // out = relu(bn(hcur)) @ out_w^T + out_b  (BN fused in staging)
    out_mfma<<<GGRID, 256, 0, stream>>>(hcur, bnp + 2 * 256, wo48, out_b, out);
}

// Round 15
// 177.391 us; speedup vs baseline: 1.0507x; 1.0507x over previous
//
#include <hip/hip_runtime.h>
#include <hip/hip_bf16.h>

#define NN 50000
#define EE 640000
#define HD 128
#define NCLS 40
#define BN_EPS 1e-5f
#define GTILES 1563  // ceil(NN/32)
#define GGRID 782    // gemm grid: each block does tiles {bid, bid+GGRID}
#define NB 98        // dst buckets of 512 nodes
#define ECHUNK 5000  // EE / 128

typedef short bf16x8 __attribute__((ext_vector_type(8)));
typedef float f32x4 __attribute__((ext_vector_type(4)));

__device__ __forceinline__ short f2bf(float f) {
    __hip_bfloat16 h = __float2bfloat16(f);
    return *reinterpret_cast<short*>(&h);
}
__device__ __forceinline__ float bflo(unsigned int v) { return __uint_as_float(v << 16); }
__device__ __forceinline__ float bfhi(unsigned int v) { return __uint_as_float(v & 0xffff0000u); }
__device__ __forceinline__ unsigned int packbf(float a, float b) {
    return (unsigned)(unsigned short)f2bf(a) | ((unsigned)(unsigned short)f2bf(b) << 16);
}

// Self-detect edge dtype per block: sample src region as int64; int32 data reinterpreted
// as int64 is out of [0,NN) with overwhelming probability per sample.
__device__ __forceinline__ bool detect_narrow(const void* ei, int* lflag, int e0, int t, int nt) {
    if (t == 0) *lflag = 0;
    __syncthreads();
    const long long* p64 = (const long long*)ei;
    long long v = p64[e0 + (t % 512) * 9];  // 512 samples spread over the 5000-edge chunk
    if (v < 0 || v >= NN) atomicOr(lflag, 1);
    __syncthreads();
    return *lflag != 0;
}

// ---------------- per-(block,bucket) histogram (LDS only) ----------------
__global__ __launch_bounds__(512) void hist_kernel(const void* __restrict__ ei,
                                                   int* __restrict__ cnt) {
    __shared__ int lh[NB];
    __shared__ int nflag;
    int t = threadIdx.x, b = blockIdx.x;
    if (t < NB) lh[t] = 0;
    bool narrow = detect_narrow(ei, &nflag, b * ECHUNK, t, 512);
    int e0 = b * ECHUNK;
    for (int e = e0 + t; e < e0 + ECHUNK; e += 512) {
        int d = narrow ? ((const int*)ei)[EE + e] : (int)((const long long*)ei)[EE + e];
        atomicAdd(&lh[d >> 9], 1);
    }
    __syncthreads();
    if (t < NB) cnt[b * NB + t] = lh[t];
}

// ---------------- bucket bases + per-(block,bucket) scatter offsets ----------------
__global__ void bucket_off2(const int* __restrict__ cnt, int* __restrict__ boffs,
                            int* __restrict__ ebase) {
    __shared__ int s[128];
    int k = threadIdx.x;  // 0..127, NB active
    int tot = 0;
    if (k < NB)
        for (int b = 0; b < 128; ++b) tot += cnt[b * NB + k];
    s[k] = tot;
    __syncthreads();
    for (int o = 1; o < 128; o <<= 1) {
        int u = (k >= o) ? s[k - o] : 0;
        __syncthreads();
        s[k] += u;
        __syncthreads();
    }
    if (k < NB) {
        int base = s[k] - tot;  // exclusive
        ebase[k] = base;
        if (k == NB - 1) ebase[NB] = base + tot;  // = EE
        int run = base;
        for (int b = 0; b < 128; ++b) {
            boffs[b * NB + k] = run;
            run += cnt[b * NB + k];
        }
    }
}

// ---------------- scatter edges (packed: dstLocal<<17 | src) ----------
__global__ __launch_bounds__(512) void bucket_scatter(const void* __restrict__ ei,
                                                      const int* __restrict__ boffs,
                                                      unsigned int* __restrict__ bkt) {
    __shared__ int lc[NB];
    __shared__ int nflag;
    int t = threadIdx.x, b = blockIdx.x;
    if (t < NB) lc[t] = boffs[b * NB + t];
    bool narrow = detect_narrow(ei, &nflag, b * ECHUNK, t, 512);
    int e0 = b * ECHUNK;
    for (int e = e0 + t; e < e0 + ECHUNK; e += 512) {
        int s, d;
        if (narrow) {
            s = ((const int*)ei)[e];
            d = ((const int*)ei)[EE + e];
        } else {
            s = (int)((const long long*)ei)[e];
            d = (int)((const long long*)ei)[EE + e];
        }
        int pos = atomicAdd(&lc[d >> 9], 1);
        bkt[pos] = ((unsigned)(d & 511) << 17) | (unsigned)s;
    }
}

// ---------------- per-bucket CSR build: LDS degree+scan+adj image, coalesced out --------
__global__ __launch_bounds__(512) void bucket_build(const unsigned int* __restrict__ bkt,
                                                    const int* __restrict__ ebase,
                                                    int* __restrict__ rowptr,
                                                    float* __restrict__ invdeg,
                                                    int* __restrict__ adj) {
    __shared__ int ldeg[512];
    __shared__ int lcur[512];
    __shared__ int ladj[8192];
    int t = threadIdx.x, k = blockIdx.x;
    int nodeBase = k << 9;
    int nn = NN - nodeBase;
    if (nn > 512) nn = 512;
    int e0 = ebase[k], e1 = ebase[k + 1];
    int ne = e1 - e0;
    ldeg[t] = 0;
    __syncthreads();
    for (int i = e0 + t; i < e1; i += 512)
        atomicAdd(&ldeg[bkt[i] >> 17], 1);
    __syncthreads();
    int d = ldeg[t];
    lcur[t] = d;
    __syncthreads();
    for (int o = 1; o < 512; o <<= 1) {  // inclusive scan
        int u = (t >= o) ? lcur[t - o] : 0;
        __syncthreads();
        lcur[t] += u;
        __syncthreads();
    }
    int excl = lcur[t] - d;
    if (t < nn) {
        rowptr[nodeBase + t] = e0 + excl;
        invdeg[nodeBase + t] = 1.0f / (float)(d > 1 ? d : 1);
    }
    if (k == 0 && t == 0) rowptr[NN] = EE;
    __syncthreads();
    lcur[t] = excl;  // reuse as cursor
    __syncthreads();
    if (ne <= 8192) {
        for (int i = e0 + t; i < e1; i += 512) {
            unsigned int p = bkt[i];
            int pos = atomicAdd(&lcur[p >> 17], 1);
            ladj[pos] = (int)(p & 0x1FFFFu);
        }
        __syncthreads();
        for (int i = t; i < ne; i += 512) adj[e0 + i] = ladj[i];
    } else {  // overflow fallback (never for this graph; correctness net)
        for (int i = e0 + t; i < e1; i += 512) {
            unsigned int p = bkt[i];
            int pos = atomicAdd(&lcur[p >> 17], 1);
            adj[e0 + pos] = (int)(p & 0x1FFFFu);
        }
    }
}

// ---------------- merged weight prep: y<4 combine; y==4 fc0->bf16; y==5 out_w->bf16x48 --
__global__ void prep_w(const float* __restrict__ Ww, const float* __restrict__ linl,
                       const float* __restrict__ linr, const float* __restrict__ fc0w,
                       const float* __restrict__ outw, ushort* __restrict__ Wcb,
                       ushort* __restrict__ wfc0, ushort* __restrict__ wo48) {
    __shared__ float wrow[HD];
    int k = threadIdx.x;
    int m = blockIdx.x;
    int which = blockIdx.y;
    if (which < 4) {  // Wc[which] = bf16(W_w @ lin_{l/r}[layer])
        const float* lin = ((which & 1) ? linr : linl) + (which >> 1) * HD * HD;
        wrow[k] = Ww[m * HD + k];
        __syncthreads();
        float acc = 0.f;
        for (int j = 0; j < HD; ++j) acc += wrow[j] * lin[j * HD + k];
        Wcb[which * HD * HD + m * HD + k] = (unsigned short)f2bf(acc);
    } else if (which == 4) {
        wfc0[m * HD + k] = (unsigned short)f2bf(fc0w[m * HD + k]);
    } else {
        if (m < 48) wo48[m * HD + k] = (m < NCLS) ? (unsigned short)f2bf(outw[m * HD + k]) : (unsigned short)0;
    }
}

// ---------------- fc0 GEMM: fp32 A staged->bf16, direct weight frags, stat partials -----
__global__ __launch_bounds__(256) void gemm_fc0(const float* __restrict__ X,
                                                const ushort* __restrict__ W1,
                                                ushort* __restrict__ Y,
                                                float* __restrict__ parts) {
    __shared__ __align__(16) char lds[16384];
    const int t = threadIdx.x;
    const int l = t & 63, w = t >> 6;
    const int lr = l & 15, lg = l >> 4;

    bf16x8 bw1[2][4];
#pragma unroll
    for (int cc = 0; cc < 2; ++cc)
#pragma unroll
        for (int kk = 0; kk < 4; ++kk)
            bw1[cc][kk] = *(const bf16x8*)&W1[(size_t)((w * 2 + cc) * 16 + lr) * HD + kk * 32 + lg * 8];

    const int t0 = blockIdx.x;
    const int t1 = blockIdx.x + GGRID;
    const bool has2 = (t1 < GTILES);

    f32x4 ss[2] = {}, sq[2] = {};
    uint4 fx[4];
    auto stage_load = [&](int tile) {
#pragma unroll
        for (int s = 0; s < 2; ++s) {
            int o = s * 4096 + t * 16;
            int po = o ^ (((o >> 8) & 7) << 4);
            int grow = tile * 32 + (po >> 8);
            if (grow > NN - 1) grow = NN - 1;
            const char* src = (const char*)X + (size_t)grow * 512 + (size_t)(po & 255) * 2;
            fx[s * 2] = *(const uint4*)src;
            fx[s * 2 + 1] = *(const uint4*)(src + 16);
        }
    };
    auto stage_write = [&](int buf) {
        char* base = lds + buf * 8192;
#pragma unroll
        for (int s = 0; s < 2; ++s) {
            uint4 a = fx[s * 2], b2 = fx[s * 2 + 1];
            uint4 v;
            v.x = packbf(__uint_as_float(a.x), __uint_as_float(a.y));
            v.y = packbf(__uint_as_float(a.z), __uint_as_float(a.w));
            v.z = packbf(__uint_as_float(b2.x), __uint_as_float(b2.y));
            v.w = packbf(__uint_as_float(b2.z), __uint_as_float(b2.w));
            *(uint4*)(base + s * 4096 + t * 16) = v;
        }
    };
    auto compute = [&](int tile, int buf) {
        const char* base = lds + buf * 8192;
        f32x4 acc[2][2] = {};
#pragma unroll
        for (int rf = 0; rf < 2; ++rf) {
            int rowb = (rf * 16 + lr) * 256;
            int sw = (lr & 7) << 4;
            bf16x8 a1[4];
#pragma unroll
            for (int kk = 0; kk < 4; ++kk)
                a1[kk] = *(const bf16x8*)(base + rowb + ((kk * 64 + lg * 16) ^ sw));
#pragma unroll
            for (int kk = 0; kk < 4; ++kk)
#pragma unroll
                for (int cc = 0; cc < 2; ++cc)
                    acc[rf][cc] = __builtin_amdgcn_mfma_f32_16x16x32_bf16(bw1[cc][kk], a1[kk], acc[rf][cc], 0, 0, 0);
        }
#pragma unroll
        for (int rf = 0; rf < 2; ++rf) {
            int row = tile * 32 + rf * 16 + lr;
            if (row < NN) {
#pragma unroll
                for (int cc = 0; cc < 2; ++cc) {
                    f32x4 v = acc[rf][cc];
                    uint2 o;
                    o.x = packbf(v[0], v[1]);
                    o.y = packbf(v[2], v[3]);
                    *(uint2*)&Y[(size_t)row * HD + (w * 2 + cc) * 16 + lg * 4] = o;
                    ss[cc] += v;
                    sq[cc] += v * v;
                }
            }
        }
    };

    stage_load(t0);
    stage_write(0);
    if (has2) stage_load(t1);
    __syncthreads();
    compute(t0, 0);
    if (has2) {
        stage_write(1);
        __syncthreads();
        compute(t1, 1);
    }

#pragma unroll
    for (int cc = 0; cc < 2; ++cc)
#pragma unroll
        for (int j = 0; j < 4; ++j) {
            float a = ss[cc][j], b = sq[cc][j];
#pragma unroll
            for (int m = 1; m < 16; m <<= 1) {
                a += __shfl_xor(a, m);
                b += __shfl_xor(b, m);
            }
            if (lr == 0) {
                int col = (w * 2 + cc) * 16 + lg * 4 + j;
                parts[(size_t)col * GTILES + blockIdx.x] = a;
                parts[(size_t)(HD + col) * GTILES + blockIdx.x] = b;
            }
        }
}

// ---------------- dual GEMM: Y = bf16(A1@W1^T + relu(bn(A2))@W2^T) + stat partials -------
__global__ __launch_bounds__(256) void gemm_dual(const ushort* __restrict__ A1g,
                                                 const ushort* __restrict__ A2g,
                                                 const float* __restrict__ bnp,
                                                 const ushort* __restrict__ W1,
                                                 const ushort* __restrict__ W2,
                                                 ushort* __restrict__ Y,
                                                 float* __restrict__ parts) {
    __shared__ __align__(16) char lds[32768];
    const int t = threadIdx.x;
    const int l = t & 63, w = t >> 6;
    const int lr = l & 15, lg = l >> 4;

    bf16x8 bw1[2][4], bw2[2][4];
#pragma unroll
    for (int cc = 0; cc < 2; ++cc)
#pragma unroll
        for (int kk = 0; kk < 4; ++kk) {
            size_t wb = (size_t)((w * 2 + cc) * 16 + lr) * HD + kk * 32 + lg * 8;
            bw1[cc][kk] = *(const bf16x8*)&W1[wb];
            bw2[cc][kk] = *(const bf16x8*)&W2[wb];
        }

    const int t0 = blockIdx.x;
    const int t1 = blockIdx.x + GGRID;
    const bool has2 = (t1 < GTILES);

    f32x4 ss[2] = {}, sq[2] = {};

    uint4 st1[2], st2[2];
    auto stage_load = [&](int tile) {
#pragma unroll
        for (int s = 0; s < 2; ++s) {
            int o = s * 4096 + t * 16;
            int po = o ^ (((o >> 8) & 7) << 4);
            int grow = tile * 32 + (po >> 8);
            if (grow > NN - 1) grow = NN - 1;
            st1[s] = *(const uint4*)((const char*)A1g + (size_t)grow * 256 + (po & 255));
            st2[s] = *(const uint4*)((const char*)A2g + (size_t)grow * 256 + (po & 255));
        }
    };
    auto stage_write = [&](int buf) {
        char* base = lds + buf * 16384;
#pragma unroll
        for (int s = 0; s < 2; ++s) {
            int o = s * 4096 + t * 16;
            *(uint4*)(base + o) = st1[s];
            int po = o ^ (((o >> 8) & 7) << 4);
            int col0 = (po & 255) >> 1;  // 8 consecutive cols
            float4 sa = *(const float4*)&bnp[col0];
            float4 sb = *(const float4*)&bnp[col0 + 4];
            float4 ba = *(const float4*)&bnp[HD + col0];
            float4 bb2 = *(const float4*)&bnp[HD + col0 + 4];
            uint4 h;
            h.x = packbf(fmaxf(bflo(st2[s].x) * sa.x + ba.x, 0.f),
                         fmaxf(bfhi(st2[s].x) * sa.y + ba.y, 0.f));
            h.y = packbf(fmaxf(bflo(st2[s].y) * sa.z + ba.z, 0.f),
                         fmaxf(bfhi(st2[s].y) * sa.w + ba.w, 0.f));
            h.z = packbf(fmaxf(bflo(st2[s].z) * sb.x + bb2.x, 0.f),
                         fmaxf(bfhi(st2[s].z) * sb.y + bb2.y, 0.f));
            h.w = packbf(fmaxf(bflo(st2[s].w) * sb.z + bb2.z, 0.f),
                         fmaxf(bfhi(st2[s].w) * sb.w + bb2.w, 0.f));
            *(uint4*)(base + 8192 + o) = h;
        }
    };
    auto compute = [&](int tile, int buf) {
        const char* base = lds + buf * 16384;
        f32x4 acc[2][2] = {};
#pragma unroll
        for (int rf = 0; rf < 2; ++rf) {
            int rowb = (rf * 16 + lr) * 256;
            int sw = (lr & 7) << 4;
            bf16x8 a1[4], a2[4];
#pragma unroll
            for (int kk = 0; kk < 4; ++kk) {
                int q = rowb + ((kk * 64 + lg * 16) ^ sw);
                a1[kk] = *(const bf16x8*)(base + q);
                a2[kk] = *(const bf16x8*)(base + 8192 + q);
            }
#pragma unroll
            for (int kk = 0; kk < 4; ++kk)
#pragma unroll
                for (int cc = 0; cc < 2; ++cc) {
                    acc[rf][cc] = __builtin_amdgcn_mfma_f32_16x16x32_bf16(bw1[cc][kk], a1[kk], acc[rf][cc], 0, 0, 0);
                    acc[rf][cc] = __builtin_amdgcn_mfma_f32_16x16x32_bf16(bw2[cc][kk], a2[kk], acc[rf][cc], 0, 0, 0);
                }
        }
#pragma unroll
        for (int rf = 0; rf < 2; ++rf) {
            int row = tile * 32 + rf * 16 + lr;
            if (row < NN) {
#pragma unroll
                for (int cc = 0; cc < 2; ++cc) {
                    f32x4 v = acc[rf][cc];
                    uint2 o;
                    o.x = packbf(v[0], v[1]);
                    o.y = packbf(v[2], v[3]);
                    *(uint2*)&Y[(size_t)row * HD + (w * 2 + cc) * 16 + lg * 4] = o;
                    ss[cc] += v;
                    sq[cc] += v * v;
                }
            }
        }
    };

    stage_load(t0);
    stage_write(0);
    if (has2) stage_load(t1);  // in flight during compute(t0)
    __syncthreads();
    compute(t0, 0);
    if (has2) {
        stage_write(1);
        __syncthreads();
        compute(t1, 1);
    }

#pragma unroll
    for (int cc = 0; cc < 2; ++cc)
#pragma unroll
        for (int j = 0; j < 4; ++j) {
            float a = ss[cc][j], b = sq[cc][j];
#pragma unroll
            for (int m = 1; m < 16; m <<= 1) {
                a += __shfl_xor(a, m);
                b += __shfl_xor(b, m);
            }
            if (lr == 0) {
                int col = (w * 2 + cc) * 16 + lg * 4 + j;
                parts[(size_t)col * GTILES + blockIdx.x] = a;
                parts[(size_t)(HD + col) * GTILES + blockIdx.x] = b;
            }
        }
}

// ---------------- BN fold: block j reduces n partials for col j -> bnp ----------------
__global__ __launch_bounds__(256) void bn_fold2(const float* __restrict__ parts, int n,
                                                const float* __restrict__ scale,
                                                const float* __restrict__ bias,
                                                float* __restrict__ bnp) {
    __shared__ float r1[256], r2[256];
    int j = blockIdx.x;   // 0..127 column
    int t = threadIdx.x;  // 256
    float a = 0.f, b = 0.f;
    for (int i = t; i < n; i += 256) {
        a += parts[(size_t)j * GTILES + i];
        b += parts[(size_t)(HD + j) * GTILES + i];
    }
    r1[t] = a; r2[t] = b;
    __syncthreads();
    for (int o = 128; o; o >>= 1) {
        if (t < o) { r1[t] += r1[t + o]; r2[t] += r2[t + o]; }
        __syncthreads();
    }
    if (t == 0) {
        float mu = r1[0] * (1.0f / NN);
        float var = r2[0] * (1.0f / NN) - mu * mu;
        float sc = scale[j] * rsqrtf(var + BN_EPS);
        bnp[j] = sc;
        bnp[HD + j] = bias[j] - mu * sc;
    }
}

// ---------------- aggregation v4: 16 neighbors in flight, BN+ReLU fused ----------------
__global__ __launch_bounds__(256) void agg_kernel(const ushort* __restrict__ Hp,
                                                  const float* __restrict__ bnp,
                                                  const int* __restrict__ adj,
                                                  const int* __restrict__ rowptr,
                                                  const float* __restrict__ invdeg,
                                                  ushort* __restrict__ A) {
    int node = blockIdx.x * 4 + (threadIdx.x >> 6);
    if (node >= NN) return;
    int l = threadIdx.x & 63;
    int slot = l >> 4, col = l & 15;
    float sc[8], bi[8];
    {
        float4 a = *(const float4*)&bnp[col * 8];
        float4 b = *(const float4*)&bnp[col * 8 + 4];
        float4 c = *(const float4*)&bnp[HD + col * 8];
        float4 d = *(const float4*)&bnp[HD + col * 8 + 4];
        sc[0] = a.x; sc[1] = a.y; sc[2] = a.z; sc[3] = a.w;
        sc[4] = b.x; sc[5] = b.y; sc[6] = b.z; sc[7] = b.w;
        bi[0] = c.x; bi[1] = c.y; bi[2] = c.z; bi[3] = c.w;
        bi[4] = d.x; bi[5] = d.y; bi[6] = d.z; bi[7] = d.w;
    }
    int b = rowptr[node], e = rowptr[node + 1];
    float id = invdeg[node];
    float acc[8] = {};
    for (int i = b; i < e; i += 16) {
        int i0 = i + slot, i1 = i + 4 + slot, i2 = i + 8 + slot, i3 = i + 12 + slot;
        bool v0 = i0 < e, v1 = i1 < e, v2 = i2 < e, v3 = i3 < e;
        int s0 = adj[v0 ? i0 : i];
        int s1 = adj[v1 ? i1 : i];
        int s2 = adj[v2 ? i2 : i];
        int s3 = adj[v3 ? i3 : i];
        uint4 a0 = *(const uint4*)&Hp[(size_t)s0 * HD + col * 8];
        uint4 a1 = *(const uint4*)&Hp[(size_t)s1 * HD + col * 8];
        uint4 a2 = *(const uint4*)&Hp[(size_t)s2 * HD + col * 8];
        uint4 a3 = *(const uint4*)&Hp[(size_t)s3 * HD + col * 8];
        float m0 = v0 ? 1.f : 0.f, m1 = v1 ? 1.f : 0.f;
        float m2 = v2 ? 1.f : 0.f, m3 = v3 ? 1.f : 0.f;
#define TERM(k, lo, word)                                                            \
        acc[k] += fmaxf(lo(a0.word) * sc[k] + bi[k], 0.f) * m0 +                      \
                  fmaxf(lo(a1.word) * sc[k] + bi[k], 0.f) * m1 +                      \
                  fmaxf(lo(a2.word) * sc[k] + bi[k], 0.f) * m2 +                      \
                  fmaxf(lo(a3.word) * sc[k] + bi[k], 0.f) * m3
        TERM(0, bflo, x); TERM(1, bfhi, x);
        TERM(2, bflo, y); TERM(3, bfhi, y);
        TERM(4, bflo, z); TERM(5, bfhi, z);
        TERM(6, bflo, w); TERM(7, bfhi, w);
#undef TERM
    }
#pragma unroll
    for (int c2 = 0; c2 < 8; ++c2) {
        acc[c2] += __shfl_xor(acc[c2], 16);
        acc[c2] += __shfl_xor(acc[c2], 32);
    }
    if (slot == 0) {
        uint4 o;
        o.x = packbf(acc[0] * id, acc[1] * id);
        o.y = packbf(acc[2] * id, acc[3] * id);
        o.z = packbf(acc[4] * id, acc[5] * id);
        o.w = packbf(acc[6] * id, acc[7] * id);
        *(uint4*)&A[(size_t)node * HD + col * 8] = o;
    }
}

// ---------------- output: MFMA with fused BN on staging, fp32 out + bias ----------------
__global__ __launch_bounds__(256) void out_mfma(const ushort* __restrict__ Hp,
                                                const float* __restrict__ bnp,
                                                const ushort* __restrict__ W48,
                                                const float* __restrict__ B,
                                                float* __restrict__ out) {
    __shared__ __align__(16) char lds[16384];
    __shared__ float blds[48];
    const int t = threadIdx.x;
    const int l = t & 63;
    const int lr = l & 15, lg = l >> 4;
    if (t < 48) blds[t] = (t < NCLS) ? B[t] : 0.f;

    bf16x8 bw[3][4];
#pragma unroll
    for (int cc = 0; cc < 3; ++cc)
#pragma unroll
        for (int kk = 0; kk < 4; ++kk)
            bw[cc][kk] = *(const bf16x8*)&W48[(size_t)(cc * 16 + lr) * HD + kk * 32 + lg * 8];

    const int t0 = blockIdx.x, t1 = blockIdx.x + GGRID;
    const bool has2 = (t1 < GTILES);

    uint4 s1a[2];
    auto stage_load = [&](int tile) {
#pragma unroll
        for (int s = 0; s < 2; ++s) {
            int o = s * 4096 + t * 16;
            int po = o ^ (((o >> 8) & 7) << 4);
            int grow = tile * 32 + (po >> 8);
            if (grow > NN - 1) grow = NN - 1;
            s1a[s] = *(const uint4*)((const char*)Hp + (size_t)grow * 256 + (po & 255));
        }
    };
    auto stage_write = [&](int buf) {
        char* base = lds + buf * 8192;
#pragma unroll
        for (int s = 0; s < 2; ++s) {
            int o = s * 4096 + t * 16;
            int po = o ^ (((o >> 8) & 7) << 4);
            int col0 = (po & 255) >> 1;
            float4 sa = *(const float4*)&bnp[col0];
            float4 sb = *(const float4*)&bnp[col0 + 4];
            float4 ba = *(const float4*)&bnp[HD + col0];
            float4 bb2 = *(const float4*)&bnp[HD + col0 + 4];
            uint4 h;
            h.x = packbf(fmaxf(bflo(s1a[s].x) * sa.x + ba.x, 0.f),
                         fmaxf(bfhi(s1a[s].x) * sa.y + ba.y, 0.f));
            h.y = packbf(fmaxf(bflo(s1a[s].y) * sa.z + ba.z, 0.f),
                         fmaxf(bfhi(s1a[s].y) * sa.w + ba.w, 0.f));
            h.z = packbf(fmaxf(bflo(s1a[s].z) * sb.x + bb2.x, 0.f),
                         fmaxf(bfhi(s1a[s].z) * sb.y + bb2.y, 0.f));
            h.w = packbf(fmaxf(bflo(s1a[s].w) * sb.z + bb2.z, 0.f),
                         fmaxf(bfhi(s1a[s].w) * sb.w + bb2.w, 0.f));
            *(uint4*)(base + o) = h;
        }
    };
    auto compute = [&](int tile, int buf) {
        const char* base = lds + buf * 8192;
        f32x4 acc[2][3] = {};
#pragma unroll
        for (int rf = 0; rf < 2; ++rf) {
            int rowb = (rf * 16 + lr) * 256;
            int sw = (lr & 7) << 4;
            bf16x8 a1[4];
#pragma unroll
            for (int kk = 0; kk < 4; ++kk)
                a1[kk] = *(const bf16x8*)(base + rowb + ((kk * 64 + lg * 16) ^ sw));
#pragma unroll
            for (int kk = 0; kk < 4; ++kk)
#pragma unroll
                for (int cc = 0; cc < 3; ++cc)
                    acc[rf][cc] = __builtin_amdgcn_mfma_f32_16x16x32_bf16(bw[cc][kk], a1[kk], acc[rf][cc], 0, 0, 0);
        }
#pragma unroll
        for (int rf = 0; rf < 2; ++rf) {
            int row = tile * 32 + rf * 16 + lr;
            if (row < NN) {
#pragma unroll
                for (int cc = 0; cc < 3; ++cc) {
                    int col = cc * 16 + lg * 4;
                    if (col < NCLS) {
                        float4 bv = *(const float4*)&blds[col];
                        float2 lo = {acc[rf][cc][0] + bv.x, acc[rf][cc][1] + bv.y};
                        float2 hi = {acc[rf][cc][2] + bv.z, acc[rf][cc][3] + bv.w};
                        *(float2*)&out[(size_t)row * NCLS + col] = lo;
                        *(float2*)&out[(size_t)row * NCLS + col + 2] = hi;
                    }
                }
            }
        }
    };

    stage_load(t0);
    stage_write(0);
    if (has2) stage_load(t1);
    __syncthreads();
    compute(t0, 0);
    if (has2) {
        stage_write(1);
        __syncthreads();
        compute(t1, 1);
    }
}

extern "C" void kernel_launch(void* const* d_in, const int* in_sizes, int n_in,
                              void* d_out, int out_size, void* d_ws, size_t ws_size,
                              hipStream_t stream) {
    const float* x = (const float*)d_in[0];
    const void* ei = d_in[1];
    const float* fc0_w = (const float*)d_in[2];
    const float* bn_scale = (const float*)d_in[4];
    const float* bn_bias = (const float*)d_in[5];
    const float* lin_l = (const float*)d_in[6];
    const float* lin_r = (const float*)d_in[7];
    const float* W_w = (const float*)d_in[8];
    const float* out_w = (const float*)d_in[10];
    const float* out_b = (const float*)d_in[11];
    float* out = (float*)d_out;

    // ---- workspace carve-up (256B aligned) ----
    char* p = (char*)d_ws;
    auto alloc = [&](size_t bytes) -> void* {
        void* r = (void*)p;
        p += (bytes + 255) & ~(size_t)255;
        return r;
    };
    int* rowptr = (int*)alloc((NN + 1) * 4);
    float* invdeg = (float*)alloc(NN * 4);
    int* adj = (int*)alloc(EE * 4);
    int* cnt = (int*)alloc(128 * NB * 4);
    int* boffs = (int*)alloc(128 * NB * 4);
    int* ebase = (int*)alloc((NB + 1) * 4);
    unsigned int* bkt = (unsigned int*)alloc((size_t)EE * 4);
    float* parts = (float*)alloc((size_t)256 * GTILES * 4);  // stat partials [256][1563]
    float* bnp = (float*)alloc(3 * 256 * 4);        // [3][scale128|bias128]
    ushort* Wcb = (ushort*)alloc(4 * HD * HD * 2);  // [layer][l/r][128][128] bf16
    ushort* wfc0 = (ushort*)alloc(HD * HD * 2);     // fc0_w bf16
    ushort* wo48 = (ushort*)alloc(48 * HD * 2);     // out_w bf16 zero-padded to 48 rows
    ushort* hpreA = (ushort*)alloc((size_t)NN * HD * 2);  // pre-BN activations (bf16)
    ushort* hpreB = (ushort*)alloc((size_t)NN * HD * 2);
    ushort* aggb = (ushort*)alloc((size_t)NN * HD * 2);

    // graph build: hist (self-detect) -> offsets -> scatter -> per-bucket build
    hist_kernel<<<128, 512, 0, stream>>>(ei, cnt);
    bucket_off2<<<1, 128, 0, stream>>>(cnt, boffs, ebase);
    bucket_scatter<<<128, 512, 0, stream>>>(ei, boffs, bkt);
    bucket_build<<<NB, 512, 0, stream>>>(bkt, ebase, rowptr, invdeg, adj);

    // merged weight prep (combine + fc0 conv + out conv)
    prep_w<<<dim3(HD, 6), HD, 0, stream>>>(W_w, lin_l, lin_r, fc0_w, out_w, Wcb, wfc0, wo48);

    // fc0 (reads fp32 x directly) -> hpreA + stats (fc0_b dropped: cancelled by BN)
    gemm_fc0<<<GGRID, 256, 0, stream>>>(x, wfc0, hpreA, parts);
    bn_fold2<<<128, 256, 0, stream>>>(parts, GGRID, bn_scale, bn_bias, bnp);

    ushort* hcur = hpreA;
    ushort* hnext = hpreB;
    for (int layer = 0; layer < 2; ++layer) {
        float* bp = bnp + layer * 256;
        const ushort* Wl = Wcb + (size_t)(layer * 2 + 0) * HD * HD;
        const ushort* Wr = Wcb + (size_t)(layer * 2 + 1) * HD * HD;
        // agg applies BN+ReLU on the fly from pre-BN hcur (max-occupancy gather dispatch)
        agg_kernel<<<(NN + 3) / 4, 256, 0, stream>>>(hcur, bp, adj, rowptr, invdeg, aggb);
        // fused: hnext = bf16(aggb@Wl^T + relu(bn(hcur))@Wr^T) + stat partials
        gemm_dual<<<GGRID, 256, 0, stream>>>(aggb, hcur, bp, Wl, Wr, hnext, parts);
        bn_fold2<<<128, 256, 0, stream>>>(parts, GGRID, bn_scale + (layer + 1) * HD,
                                          bn_bias + (layer + 1) * HD, bnp + (layer + 1) * 256);
        ushort* tmp = hcur; hcur = hnext; hnext = tmp;
    }

    // out = relu(bn(hcur)) @ out_w^T + out_b  (BN fused in staging)
    out_mfma<<<GGRID, 256, 0, stream>>>(hcur, bnp + 2 * 256, wo48, out_b, out);
}